// Round 1
// baseline (3716.083 us; speedup 1.0000x reference)
//
#include <hip/hip_runtime.h>
#include <hip/hip_bf16.h>

#define N_NODES 50000
#define E_EDGES 800000

// ---------------- degree ----------------
__global__ void deg_kernel(const int* __restrict__ dst, float* __restrict__ deg, int E) {
    int e = blockIdx.x * blockDim.x + threadIdx.x;
    if (e < E) atomicAdd(&deg[dst[e]], 1.0f);
}

__global__ void rdeg_kernel(float* __restrict__ deg, int N) {
    int n = blockIdx.x * blockDim.x + threadIdx.x;
    if (n < N) deg[n] = 1.0f / fmaxf(deg[n], 1.0f);
}

// ---------------- scatter-sum, d=128 (one wave per edge, float2 per lane) ----
__global__ void scatter128_kernel(const float* __restrict__ x,
                                  const int* __restrict__ src,
                                  const int* __restrict__ dst,
                                  float* __restrict__ sum, int E) {
    int t = blockIdx.x * blockDim.x + threadIdx.x;
    int e = t >> 6;
    int lane = t & 63;
    if (e >= E) return;
    int s = src[e];
    int d = dst[e];
    const float2 v = *reinterpret_cast<const float2*>(x + (size_t)s * 128 + lane * 2);
    float* p = sum + (size_t)d * 128 + lane * 2;
    atomicAdd(p + 0, v.x);
    atomicAdd(p + 1, v.y);
}

// ---------------- scatter-sum, d=256 (one wave per edge, float4 per lane) ----
__global__ void scatter256_kernel(const float* __restrict__ h,
                                  const int* __restrict__ src,
                                  const int* __restrict__ dst,
                                  float* __restrict__ sum, int E) {
    int t = blockIdx.x * blockDim.x + threadIdx.x;
    int e = t >> 6;
    int lane = t & 63;
    if (e >= E) return;
    int s = src[e];
    int d = dst[e];
    const float4 v = *reinterpret_cast<const float4*>(h + (size_t)s * 256 + lane * 4);
    float* p = sum + (size_t)d * 256 + lane * 4;
    atomicAdd(p + 0, v.x);
    atomicAdd(p + 1, v.y);
    atomicAdd(p + 2, v.z);
    atomicAdd(p + 3, v.w);
}

// ---------------- layer 1: h = relu(agg1 @ W1l + b1 + x @ W1r) ---------------
// 16 rows per block, 256 threads (one output column j per thread).
__global__ __launch_bounds__(256) void gemm1_kernel(
        const float* __restrict__ x, const float* __restrict__ sum1,
        const float* __restrict__ rdeg,
        const float* __restrict__ W1l, const float* __restrict__ W1r,
        const float* __restrict__ b1, float* __restrict__ h) {
    __shared__ float xs[16][128];
    __shared__ float as[16][128];
    const int n0 = blockIdx.x * 16;
    const int tid = threadIdx.x;

    for (int i = tid; i < 16 * 128; i += 256) {
        int r = i >> 7, k = i & 127;
        int n = n0 + r;
        xs[r][k] = x[(size_t)n * 128 + k];
        as[r][k] = sum1[(size_t)n * 128 + k] * rdeg[n];
    }
    __syncthreads();

    float acc[16];
#pragma unroll
    for (int r = 0; r < 16; ++r) acc[r] = 0.0f;

    const int j = tid;  // 0..255
    for (int k = 0; k < 128; ++k) {
        float wl = W1l[k * 256 + j];
        float wr = W1r[k * 256 + j];
#pragma unroll
        for (int r = 0; r < 16; ++r) acc[r] += as[r][k] * wl + xs[r][k] * wr;
    }

    const float bb = b1[j];
#pragma unroll
    for (int r = 0; r < 16; ++r) {
        float v = acc[r] + bb;
        h[(size_t)(n0 + r) * 256 + j] = v > 0.0f ? v : 0.0f;
    }
}

// ---------------- layer 2: out = agg2 @ W2l + b2 + h @ W2r -------------------
// 16 rows per block, 256 threads: j = tid&63, row-group = tid>>6 (4 rows each).
__global__ __launch_bounds__(256) void gemm2_kernel(
        const float* __restrict__ h, const float* __restrict__ sum2,
        const float* __restrict__ rdeg,
        const float* __restrict__ W2l, const float* __restrict__ W2r,
        const float* __restrict__ b2, float* __restrict__ out) {
    __shared__ float hs[16][256];
    __shared__ float as[16][256];
    const int n0 = blockIdx.x * 16;
    const int tid = threadIdx.x;

    for (int i = tid; i < 16 * 256; i += 256) {
        int r = i >> 8, k = i & 255;
        int n = n0 + r;
        hs[r][k] = h[(size_t)n * 256 + k];
        as[r][k] = sum2[(size_t)n * 256 + k] * rdeg[n];
    }
    __syncthreads();

    const int j = tid & 63;
    const int rg = tid >> 6;  // 0..3
    float acc[4];
#pragma unroll
    for (int rr = 0; rr < 4; ++rr) acc[rr] = 0.0f;

    for (int k = 0; k < 256; ++k) {
        float wl = W2l[k * 64 + j];
        float wr = W2r[k * 64 + j];
#pragma unroll
        for (int rr = 0; rr < 4; ++rr) {
            int r = rg * 4 + rr;
            acc[rr] += as[r][k] * wl + hs[r][k] * wr;
        }
    }

    const float bb = b2[j];
#pragma unroll
    for (int rr = 0; rr < 4; ++rr) {
        int r = rg * 4 + rr;
        out[(size_t)(n0 + r) * 64 + j] = acc[rr] + bb;
    }
}

extern "C" void kernel_launch(void* const* d_in, const int* in_sizes, int n_in,
                              void* d_out, int out_size, void* d_ws, size_t ws_size,
                              hipStream_t stream) {
    const float* x   = (const float*)d_in[0];
    const int*   ei  = (const int*)d_in[1];     // [2, E] row-major: row0=src, row1=dst
    const float* W1l = (const float*)d_in[2];
    const float* W1r = (const float*)d_in[3];
    const float* b1  = (const float*)d_in[4];
    const float* W2l = (const float*)d_in[5];
    const float* W2r = (const float*)d_in[6];
    const float* b2  = (const float*)d_in[7];
    float* out = (float*)d_out;

    const int E = in_sizes[1] / 2;  // 800000
    const int N = N_NODES;

    const int* src = ei;
    const int* dst = ei + E;

    // workspace layout (floats):
    //   deg/rdeg : [0, 51200)
    //   sum1     : [51200, 51200 + N*128)
    //   sum2     : [.., + N*256)
    //   h        : [.., + N*256)
    float* ws = (float*)d_ws;
    float* deg  = ws;
    float* sum1 = ws + 51200;
    float* sum2 = sum1 + (size_t)N * 128;
    float* h    = sum2 + (size_t)N * 256;

    // zero deg + sum1 + sum2 in one shot (h is fully overwritten)
    size_t zero_bytes = (size_t)(51200 + (size_t)N * 128 + (size_t)N * 256) * sizeof(float);
    hipMemsetAsync(d_ws, 0, zero_bytes, stream);

    // degree, then rdeg = 1/max(deg,1)
    deg_kernel<<<(E + 255) / 256, 256, 0, stream>>>(dst, deg, E);
    rdeg_kernel<<<(N + 255) / 256, 256, 0, stream>>>(deg, N);

    // layer 1 scatter-sum of x  (one wave per edge)
    {
        long long threads = (long long)E * 64;
        int grid = (int)((threads + 255) / 256);
        scatter128_kernel<<<grid, 256, 0, stream>>>(x, src, dst, sum1, E);
    }

    // layer 1 fused GEMM + bias + relu
    gemm1_kernel<<<N / 16, 256, 0, stream>>>(x, sum1, deg, W1l, W1r, b1, h);

    // layer 2 scatter-sum of h
    {
        long long threads = (long long)E * 64;
        int grid = (int)((threads + 255) / 256);
        scatter256_kernel<<<grid, 256, 0, stream>>>(h, src, dst, sum2, E);
    }

    // layer 2 fused GEMM + bias
    gemm2_kernel<<<N / 16, 256, 0, stream>>>(h, sum2, deg, W2l, W2r, b2, out);
}

// Round 2
// 587.214 us; speedup vs baseline: 6.3283x; 6.3283x over previous
//
#include <hip/hip_runtime.h>
#include <hip/hip_bf16.h>

#define N_NODES 50000

// ---------------- CSR build ----------------
__global__ void hist_kernel(const int* __restrict__ dst, int* __restrict__ cnt, int E) {
    int e = blockIdx.x * blockDim.x + threadIdx.x;
    if (e < E) atomicAdd(&cnt[dst[e]], 1);
}

__global__ __launch_bounds__(256) void scan_kernel(const int* __restrict__ cnt,
                                                   int* __restrict__ rowptr, int N) {
    __shared__ int part[256];
    const int tid = threadIdx.x;
    const int chunk = (N + 255) / 256;
    int begin = min(tid * chunk, N);
    int end = min(begin + chunk, N);
    int s = 0;
    for (int i = begin; i < end; ++i) s += cnt[i];
    part[tid] = s;
    __syncthreads();
    if (tid == 0) {
        int run = 0;
        for (int i = 0; i < 256; ++i) { int t = part[i]; part[i] = run; run += t; }
    }
    __syncthreads();
    int run = part[tid];
    for (int i = begin; i < end; ++i) { rowptr[i] = run; run += cnt[i]; }
    if (begin < N && end == N) rowptr[N] = run;
}

__global__ void fill_kernel(const int* __restrict__ src, const int* __restrict__ dst,
                            const int* __restrict__ rowptr, int* __restrict__ cursor,
                            int* __restrict__ eidx, int E) {
    int e = blockIdx.x * blockDim.x + threadIdx.x;
    if (e < E) {
        int d = dst[e];
        int pos = rowptr[d] + atomicAdd(&cursor[d], 1);
        eidx[pos] = src[e];
    }
}

// ---------------- gather-mean, d=128 (one wave per node, float2/lane) --------
__global__ __launch_bounds__(256) void agg128_kernel(const float* __restrict__ x,
        const int* __restrict__ rowptr, const int* __restrict__ eidx,
        float* __restrict__ agg, int N) {
    int t = blockIdx.x * blockDim.x + threadIdx.x;
    int n = t >> 6;
    int lane = t & 63;
    if (n >= N) return;
    int b = rowptr[n], e = rowptr[n + 1];
    const size_t off = (size_t)lane * 2;
    float ax = 0.0f, ay = 0.0f;
    int j = b;
    for (; j + 1 < e; j += 2) {
        int s0 = eidx[j], s1 = eidx[j + 1];
        float2 v0 = *reinterpret_cast<const float2*>(x + (size_t)s0 * 128 + off);
        float2 v1 = *reinterpret_cast<const float2*>(x + (size_t)s1 * 128 + off);
        ax += v0.x + v1.x;
        ay += v0.y + v1.y;
    }
    if (j < e) {
        int s0 = eidx[j];
        float2 v0 = *reinterpret_cast<const float2*>(x + (size_t)s0 * 128 + off);
        ax += v0.x;
        ay += v0.y;
    }
    float rd = 1.0f / (float)max(e - b, 1);
    float2 r = {ax * rd, ay * rd};
    *reinterpret_cast<float2*>(agg + (size_t)n * 128 + off) = r;
}

// ---------------- gather-mean, d=256 (one wave per node, float4/lane) --------
__global__ __launch_bounds__(256) void agg256_kernel(const float* __restrict__ h,
        const int* __restrict__ rowptr, const int* __restrict__ eidx,
        float* __restrict__ agg, int N) {
    int t = blockIdx.x * blockDim.x + threadIdx.x;
    int n = t >> 6;
    int lane = t & 63;
    if (n >= N) return;
    int b = rowptr[n], e = rowptr[n + 1];
    const size_t off = (size_t)lane * 4;
    float a0 = 0, a1 = 0, a2 = 0, a3 = 0;
    int j = b;
    for (; j + 1 < e; j += 2) {
        int s0 = eidx[j], s1 = eidx[j + 1];
        float4 v0 = *reinterpret_cast<const float4*>(h + (size_t)s0 * 256 + off);
        float4 v1 = *reinterpret_cast<const float4*>(h + (size_t)s1 * 256 + off);
        a0 += v0.x + v1.x;
        a1 += v0.y + v1.y;
        a2 += v0.z + v1.z;
        a3 += v0.w + v1.w;
    }
    if (j < e) {
        int s0 = eidx[j];
        float4 v0 = *reinterpret_cast<const float4*>(h + (size_t)s0 * 256 + off);
        a0 += v0.x; a1 += v0.y; a2 += v0.z; a3 += v0.w;
    }
    float rd = 1.0f / (float)max(e - b, 1);
    float4 r = {a0 * rd, a1 * rd, a2 * rd, a3 * rd};
    *reinterpret_cast<float4*>(agg + (size_t)n * 256 + off) = r;
}

// ---------------- fused dual GEMM: out = A1@B1 + A2@B2 + bias (+relu) -------
// Tile: 128 rows x 64 cols, 256 threads, thread = 4 rows (stride 32) x 8 cols.
// A-tiles staged in LDS with stride 68 (conflict-free b128 reads), B via L1.
template <int K, bool RELU>
__global__ __launch_bounds__(256) void gemm_kernel(
        const float* __restrict__ A1, const float* __restrict__ A2,
        const float* __restrict__ B1, const float* __restrict__ B2,
        const float* __restrict__ bias, float* __restrict__ out,
        int M, int Ntot) {
    __shared__ float A1s[128][68];
    __shared__ float A2s[128][68];
    const int tid = threadIdx.x;
    const int n0 = blockIdx.x * 128;
    const int c0 = blockIdx.y * 64;
    const int cg = tid & 7;
    const int rg = tid >> 3;
    const int j0 = c0 + cg * 8;

    float acc[4][8];
#pragma unroll
    for (int i = 0; i < 4; ++i)
#pragma unroll
        for (int q = 0; q < 8; ++q) acc[i][q] = 0.0f;

    for (int kc = 0; kc < K; kc += 64) {
        __syncthreads();
        // stage 128x64 chunk of A1 and A2 (2048 float4 each)
        for (int l = tid; l < 2048; l += 256) {
            int r = l >> 4;
            int c4 = l & 15;
            int n = n0 + r;
            float4 v1 = {0, 0, 0, 0}, v2 = {0, 0, 0, 0};
            if (n < M) {
                v1 = *reinterpret_cast<const float4*>(A1 + (size_t)n * K + kc + c4 * 4);
                v2 = *reinterpret_cast<const float4*>(A2 + (size_t)n * K + kc + c4 * 4);
            }
            *reinterpret_cast<float4*>(&A1s[r][c4 * 4]) = v1;
            *reinterpret_cast<float4*>(&A2s[r][c4 * 4]) = v2;
        }
        __syncthreads();

        for (int k = 0; k < 64; k += 4) {
            float a1[4][4], a2[4][4];
#pragma unroll
            for (int i = 0; i < 4; ++i) {
                float4 t1 = *reinterpret_cast<const float4*>(&A1s[rg + 32 * i][k]);
                float4 t2 = *reinterpret_cast<const float4*>(&A2s[rg + 32 * i][k]);
                a1[i][0] = t1.x; a1[i][1] = t1.y; a1[i][2] = t1.z; a1[i][3] = t1.w;
                a2[i][0] = t2.x; a2[i][1] = t2.y; a2[i][2] = t2.z; a2[i][3] = t2.w;
            }
#pragma unroll
            for (int kk = 0; kk < 4; ++kk) {
                const float* brow1 = B1 + (size_t)(kc + k + kk) * Ntot + j0;
                const float* brow2 = B2 + (size_t)(kc + k + kk) * Ntot + j0;
                float4 b1a = *reinterpret_cast<const float4*>(brow1);
                float4 b1b = *reinterpret_cast<const float4*>(brow1 + 4);
                float4 b2a = *reinterpret_cast<const float4*>(brow2);
                float4 b2b = *reinterpret_cast<const float4*>(brow2 + 4);
#pragma unroll
                for (int i = 0; i < 4; ++i) {
                    float va = a1[i][kk], vb = a2[i][kk];
                    acc[i][0] += va * b1a.x + vb * b2a.x;
                    acc[i][1] += va * b1a.y + vb * b2a.y;
                    acc[i][2] += va * b1a.z + vb * b2a.z;
                    acc[i][3] += va * b1a.w + vb * b2a.w;
                    acc[i][4] += va * b1b.x + vb * b2b.x;
                    acc[i][5] += va * b1b.y + vb * b2b.y;
                    acc[i][6] += va * b1b.z + vb * b2b.z;
                    acc[i][7] += va * b1b.w + vb * b2b.w;
                }
            }
        }
    }

    const float4 bia = *reinterpret_cast<const float4*>(bias + j0);
    const float4 bib = *reinterpret_cast<const float4*>(bias + j0 + 4);
#pragma unroll
    for (int i = 0; i < 4; ++i) {
        int r = n0 + rg + 32 * i;
        if (r < M) {
            float o[8];
            o[0] = acc[i][0] + bia.x; o[1] = acc[i][1] + bia.y;
            o[2] = acc[i][2] + bia.z; o[3] = acc[i][3] + bia.w;
            o[4] = acc[i][4] + bib.x; o[5] = acc[i][5] + bib.y;
            o[6] = acc[i][6] + bib.z; o[7] = acc[i][7] + bib.w;
            if (RELU) {
#pragma unroll
                for (int q = 0; q < 8; ++q) o[q] = o[q] > 0.0f ? o[q] : 0.0f;
            }
            float4 oa = {o[0], o[1], o[2], o[3]};
            float4 ob = {o[4], o[5], o[6], o[7]};
            *reinterpret_cast<float4*>(out + (size_t)r * Ntot + j0) = oa;
            *reinterpret_cast<float4*>(out + (size_t)r * Ntot + j0 + 4) = ob;
        }
    }
}

extern "C" void kernel_launch(void* const* d_in, const int* in_sizes, int n_in,
                              void* d_out, int out_size, void* d_ws, size_t ws_size,
                              hipStream_t stream) {
    const float* x   = (const float*)d_in[0];
    const int*   ei  = (const int*)d_in[1];
    const float* W1l = (const float*)d_in[2];
    const float* W1r = (const float*)d_in[3];
    const float* b1  = (const float*)d_in[4];
    const float* W2l = (const float*)d_in[5];
    const float* W2r = (const float*)d_in[6];
    const float* b2  = (const float*)d_in[7];
    float* out = (float*)d_out;

    const int E = in_sizes[1] / 2;
    const int N = N_NODES;
    const int* src = ei;
    const int* dst = ei + E;

    // workspace layout (bytes):
    //   cnt    : [0,        200000)       int[N]
    //   cursor : [200000,   400000)       int[N]
    //   rowptr : [400000,   600004)       int[N+1]
    //   eidx   : [600004,   600004+4E)
    //   agg    : 16-aligned, N*256 floats (used as N*128 for layer 1)
    //   h      : N*256 floats
    char* ws = (char*)d_ws;
    int* cnt    = (int*)(ws);
    int* cursor = (int*)(ws + 200000);
    int* rowptr = (int*)(ws + 400000);
    int* eidx   = (int*)(ws + 600004);
    size_t foff = (size_t)(600004 + 4 * (size_t)E);
    foff = (foff + 15) & ~(size_t)15;
    float* agg = (float*)(ws + foff);
    float* h   = (float*)(ws + foff + (size_t)N * 256 * 4);

    // zero cnt + cursor
    hipMemsetAsync(d_ws, 0, 400000, stream);

    hist_kernel<<<(E + 255) / 256, 256, 0, stream>>>(dst, cnt, E);
    scan_kernel<<<1, 256, 0, stream>>>(cnt, rowptr, N);
    fill_kernel<<<(E + 255) / 256, 256, 0, stream>>>(src, dst, rowptr, cursor, eidx, E);

    // layer 1: gather-mean of x, then h = relu(agg@W1l + b1 + x@W1r)
    agg128_kernel<<<(N + 3) / 4, 256, 0, stream>>>(x, rowptr, eidx, agg, N);
    {
        dim3 grid((N + 127) / 128, 256 / 64);
        gemm_kernel<128, true><<<grid, 256, 0, stream>>>(agg, x, W1l, W1r, b1, h, N, 256);
    }

    // layer 2: gather-mean of h, then out = agg@W2l + b2 + h@W2r
    agg256_kernel<<<(N + 3) / 4, 256, 0, stream>>>(h, rowptr, eidx, agg, N);
    {
        dim3 grid((N + 127) / 128, 64 / 64);
        gemm_kernel<256, false><<<grid, 256, 0, stream>>>(agg, h, W2l, W2r, b2, out, N, 64);
    }
}

// Round 3
// 332.296 us; speedup vs baseline: 11.1831x; 1.7671x over previous
//
#include <hip/hip_runtime.h>
#include <hip/hip_bf16.h>

#define N_NODES 50000

typedef __attribute__((ext_vector_type(8))) __bf16 bf16x8;
typedef __attribute__((ext_vector_type(4))) float f32x4;

__device__ __forceinline__ unsigned short f2bf(float f) {
    union { float f; unsigned u; } c{f};
    unsigned u = c.u;
    return (unsigned short)((u + 0x7FFFu + ((u >> 16) & 1u)) >> 16);
}
__device__ __forceinline__ float bf2f(unsigned short h) {
    union { unsigned u; float f; } c{(unsigned)h << 16};
    return c.f;
}

// ---------------- CSR build ----------------
__global__ void hist_kernel(const int* __restrict__ dst, int* __restrict__ cnt, int E) {
    int e = blockIdx.x * blockDim.x + threadIdx.x;
    if (e < E) atomicAdd(&cnt[dst[e]], 1);
}

__global__ __launch_bounds__(256) void scan_kernel(const int* __restrict__ cnt,
                                                   int* __restrict__ rowptr, int N) {
    __shared__ int part[256];
    const int tid = threadIdx.x;
    const int chunk = (N + 255) / 256;
    int begin = min(tid * chunk, N);
    int end = min(begin + chunk, N);
    int s = 0;
    for (int i = begin; i < end; ++i) s += cnt[i];
    part[tid] = s;
    __syncthreads();
    if (tid == 0) {
        int run = 0;
        for (int i = 0; i < 256; ++i) { int t = part[i]; part[i] = run; run += t; }
    }
    __syncthreads();
    int run = part[tid];
    for (int i = begin; i < end; ++i) { rowptr[i] = run; run += cnt[i]; }
    if (begin < N && end == N) rowptr[N] = run;
}

__global__ void fill_kernel(const int* __restrict__ src, const int* __restrict__ dst,
                            const int* __restrict__ rowptr, int* __restrict__ cursor,
                            int* __restrict__ eidx, int E) {
    int e = blockIdx.x * blockDim.x + threadIdx.x;
    if (e < E) {
        int d = dst[e];
        int pos = rowptr[d] + atomicAdd(&cursor[d], 1);
        eidx[pos] = src[e];
    }
}

// ---------------- convert x (f32 -> packed bf16) ----------------
__global__ void cvt_x_kernel(const float* __restrict__ x, unsigned* __restrict__ xb,
                             int total) {
    int t = blockIdx.x * blockDim.x + threadIdx.x;
    if (t < total) {
        float2 v = reinterpret_cast<const float2*>(x)[t];
        xb[t] = (unsigned)f2bf(v.x) | ((unsigned)f2bf(v.y) << 16);
    }
}

// ---------------- weight prep: fragment-order bf16 ----------------
// Layout: Wb[((cb*(K/8) + kb)*16 + colin)*8 + j] = W[kb*8 + j][cb*16 + colin]
__global__ void prep_w_kernel(const float* __restrict__ W1l, const float* __restrict__ W1r,
                              const float* __restrict__ W2l, const float* __restrict__ W2r,
                              unsigned short* __restrict__ Wb1l,
                              unsigned short* __restrict__ Wb1r,
                              unsigned short* __restrict__ Wb2) {
    int t = blockIdx.x * blockDim.x + threadIdx.x;
    if (t >= 12288) return;
    int g = t & 4095;
    int colin = g & 15;
    int rest = g >> 4;
    if (t < 4096) {            // W1l: K=128 (KB8=16), N=256
        int kb = rest & 15, cb = rest >> 4;
        int col = cb * 16 + colin;
#pragma unroll
        for (int j = 0; j < 8; ++j) Wb1l[g * 8 + j] = f2bf(W1l[(kb * 8 + j) * 256 + col]);
    } else if (t < 8192) {     // W1r
        int kb = rest & 15, cb = rest >> 4;
        int col = cb * 16 + colin;
#pragma unroll
        for (int j = 0; j < 8; ++j) Wb1r[g * 8 + j] = f2bf(W1r[(kb * 8 + j) * 256 + col]);
    } else {                   // [W2l | W2r]: K=256 (KB8=32), 8 col-blocks
        int kb = rest & 31, cb = rest >> 5;
        const float* W = (cb < 4) ? W2l : W2r;
        int col = (cb < 4) ? (cb * 16 + colin) : ((cb - 4) * 16 + colin);
#pragma unroll
        for (int j = 0; j < 8; ++j) Wb2[g * 8 + j] = f2bf(W[(kb * 8 + j) * 64 + col]);
    }
}

// ---------------- gather-mean of xb (d=128 bf16), one wave/node -------------
__global__ __launch_bounds__(256) void agg1_kernel(const unsigned* __restrict__ xb,
        const int* __restrict__ rowptr, const int* __restrict__ eidx,
        unsigned* __restrict__ aggb, int N) {
    int t = blockIdx.x * 256 + threadIdx.x;
    int n = t >> 6, lane = t & 63;
    if (n >= N) return;
    int b = rowptr[n], e = rowptr[n + 1];
    float a0 = 0.0f, a1 = 0.0f;
    int j = b;
    for (; j + 1 < e; j += 2) {
        unsigned v0 = xb[(size_t)eidx[j] * 64 + lane];
        unsigned v1 = xb[(size_t)eidx[j + 1] * 64 + lane];
        a0 += bf2f(v0 & 0xFFFF) + bf2f(v1 & 0xFFFF);
        a1 += bf2f(v0 >> 16) + bf2f(v1 >> 16);
    }
    if (j < e) {
        unsigned v = xb[(size_t)eidx[j] * 64 + lane];
        a0 += bf2f(v & 0xFFFF);
        a1 += bf2f(v >> 16);
    }
    float rd = 1.0f / (float)max(e - b, 1);
    aggb[(size_t)n * 64 + lane] = (unsigned)f2bf(a0 * rd) | ((unsigned)f2bf(a1 * rd) << 16);
}

// ---------------- layer 1 MFMA: hb = relu(aggb@W1l + xb@W1r + b1) -----------
// block = 4 waves; wave = 16 rows x 256 cols. No LDS, no barriers.
__global__ __launch_bounds__(256) void gemm1_mfma(
        const unsigned short* __restrict__ xb, const unsigned short* __restrict__ aggb,
        const unsigned short* __restrict__ Wb1l, const unsigned short* __restrict__ Wb1r,
        const float* __restrict__ b1, unsigned short* __restrict__ hb, int M) {
    const int tid = threadIdx.x;
    const int wave = tid >> 6, lane = tid & 63;
    const int l16 = lane & 15, lq = lane >> 4;
    const int base_row = blockIdx.x * 64 + wave * 16;
    const int row_a = min(base_row + l16, M - 1);

    f32x4 acc[16];
#pragma unroll
    for (int i = 0; i < 16; ++i) acc[i] = (f32x4){0.f, 0.f, 0.f, 0.f};

#pragma unroll
    for (int s = 0; s < 2; ++s) {
        const unsigned short* A = (s == 0) ? aggb : xb;
        const bf16x8* W = reinterpret_cast<const bf16x8*>((s == 0) ? Wb1l : Wb1r);
#pragma unroll
        for (int ks = 0; ks < 4; ++ks) {
            bf16x8 a = *reinterpret_cast<const bf16x8*>(A + (size_t)row_a * 128 + ks * 32 + lq * 8);
            int wb = (ks * 4 + lq) * 16 + l16;
#pragma unroll
            for (int cb = 0; cb < 16; ++cb) {
                bf16x8 bfr = W[cb * 256 + wb];
                acc[cb] = __builtin_amdgcn_mfma_f32_16x16x32_bf16(a, bfr, acc[cb], 0, 0, 0);
            }
        }
    }

#pragma unroll
    for (int cb = 0; cb < 16; ++cb) {
        int col = cb * 16 + l16;
        float bias = b1[col];
#pragma unroll
        for (int r = 0; r < 4; ++r) {
            int row = base_row + lq * 4 + r;
            if (row < M) {
                float v = acc[cb][r] + bias;
                hb[(size_t)row * 256 + col] = f2bf(v > 0.0f ? v : 0.0f);
            }
        }
    }
}

// ---------------- layer 2 MFMA: [t|u] = hb @ [W2l|W2r] ----------------------
// t (cols 0..63) -> bf16 tb; u (cols 64..127) -> f32 u.
__global__ __launch_bounds__(256) void gemm2_mfma(
        const unsigned short* __restrict__ hb, const unsigned short* __restrict__ Wb2,
        unsigned short* __restrict__ tb, float* __restrict__ u, int M) {
    const int tid = threadIdx.x;
    const int wave = tid >> 6, lane = tid & 63;
    const int l16 = lane & 15, lq = lane >> 4;
    const int base_row = blockIdx.x * 64 + wave * 16;
    const int row_a = min(base_row + l16, M - 1);

    f32x4 acc[8];
#pragma unroll
    for (int i = 0; i < 8; ++i) acc[i] = (f32x4){0.f, 0.f, 0.f, 0.f};

    const bf16x8* W = reinterpret_cast<const bf16x8*>(Wb2);
#pragma unroll
    for (int ks = 0; ks < 8; ++ks) {
        bf16x8 a = *reinterpret_cast<const bf16x8*>(hb + (size_t)row_a * 256 + ks * 32 + lq * 8);
        int wb = (ks * 4 + lq) * 16 + l16;
#pragma unroll
        for (int cb = 0; cb < 8; ++cb) {
            bf16x8 bfr = W[cb * 512 + wb];
            acc[cb] = __builtin_amdgcn_mfma_f32_16x16x32_bf16(a, bfr, acc[cb], 0, 0, 0);
        }
    }

#pragma unroll
    for (int cb = 0; cb < 8; ++cb) {
#pragma unroll
        for (int r = 0; r < 4; ++r) {
            int row = base_row + lq * 4 + r;
            if (row >= M) continue;
            float v = acc[cb][r];
            if (cb < 4) tb[(size_t)row * 64 + cb * 16 + l16] = f2bf(v);
            else        u[(size_t)row * 64 + (cb - 4) * 16 + l16] = v;
        }
    }
}

// ---------------- gather-mean of tb (d=64) + u + b2 -> out ------------------
// 32 lanes per node (2 cols each).
__global__ __launch_bounds__(256) void agg2_kernel(const unsigned* __restrict__ tb,
        const float* __restrict__ u, const float* __restrict__ b2,
        const int* __restrict__ rowptr, const int* __restrict__ eidx,
        float* __restrict__ out, int N) {
    int t = blockIdx.x * 256 + threadIdx.x;
    int n = t >> 5, l = t & 31;
    if (n >= N) return;
    int b = rowptr[n], e = rowptr[n + 1];
    float a0 = 0.0f, a1 = 0.0f;
    int j = b;
    for (; j + 1 < e; j += 2) {
        unsigned v0 = tb[(size_t)eidx[j] * 32 + l];
        unsigned v1 = tb[(size_t)eidx[j + 1] * 32 + l];
        a0 += bf2f(v0 & 0xFFFF) + bf2f(v1 & 0xFFFF);
        a1 += bf2f(v0 >> 16) + bf2f(v1 >> 16);
    }
    if (j < e) {
        unsigned v = tb[(size_t)eidx[j] * 32 + l];
        a0 += bf2f(v & 0xFFFF);
        a1 += bf2f(v >> 16);
    }
    float rd = 1.0f / (float)max(e - b, 1);
    float2 uu = reinterpret_cast<const float2*>(u)[(size_t)n * 32 + l];
    float2 bb = reinterpret_cast<const float2*>(b2)[l];
    float2 o = {a0 * rd + uu.x + bb.x, a1 * rd + uu.y + bb.y};
    reinterpret_cast<float2*>(out)[(size_t)n * 32 + l] = o;
}

extern "C" void kernel_launch(void* const* d_in, const int* in_sizes, int n_in,
                              void* d_out, int out_size, void* d_ws, size_t ws_size,
                              hipStream_t stream) {
    const float* x   = (const float*)d_in[0];
    const int*   ei  = (const int*)d_in[1];
    const float* W1l = (const float*)d_in[2];
    const float* W1r = (const float*)d_in[3];
    const float* b1  = (const float*)d_in[4];
    const float* W2l = (const float*)d_in[5];
    const float* W2r = (const float*)d_in[6];
    const float* b2  = (const float*)d_in[7];
    float* out = (float*)d_out;

    const int E = in_sizes[1] / 2;
    const int N = N_NODES;
    const int* src = ei;
    const int* dst = ei + E;

    // workspace layout (bytes)
    char* ws = (char*)d_ws;
    int* cnt    = (int*)(ws);
    int* cursor = (int*)(ws + 200000);
    int* rowptr = (int*)(ws + 400000);
    int* eidx   = (int*)(ws + 600004);
    size_t off = 600004 + 4 * (size_t)E;
    off = (off + 15) & ~(size_t)15;
    unsigned short* xb   = (unsigned short*)(ws + off);  off += (size_t)N * 128 * 2;
    unsigned short* aggb = (unsigned short*)(ws + off);  off += (size_t)N * 128 * 2;
    unsigned short* hb   = (unsigned short*)(ws + off);  off += (size_t)N * 256 * 2;
    unsigned short* tb   = (unsigned short*)(ws + off);  off += (size_t)N * 64 * 2;
    float*          ubuf = (float*)(ws + off);           off += (size_t)N * 64 * 4;
    unsigned short* Wb1l = (unsigned short*)(ws + off);  off += 128 * 256 * 2;
    unsigned short* Wb1r = (unsigned short*)(ws + off);  off += 128 * 256 * 2;
    unsigned short* Wb2  = (unsigned short*)(ws + off);  off += 256 * 128 * 2;

    hipMemsetAsync(d_ws, 0, 400000, stream);  // cnt + cursor

    hist_kernel<<<(E + 255) / 256, 256, 0, stream>>>(dst, cnt, E);
    scan_kernel<<<1, 256, 0, stream>>>(cnt, rowptr, N);
    fill_kernel<<<(E + 255) / 256, 256, 0, stream>>>(src, dst, rowptr, cursor, eidx, E);

    cvt_x_kernel<<<(N * 64 + 255) / 256, 256, 0, stream>>>(x, (unsigned*)xb, N * 64);
    prep_w_kernel<<<48, 256, 0, stream>>>(W1l, W1r, W2l, W2r, Wb1l, Wb1r, Wb2);

    // layer 1
    agg1_kernel<<<(N * 64 + 255) / 256, 256, 0, stream>>>((const unsigned*)xb, rowptr, eidx,
                                                          (unsigned*)aggb, N);
    gemm1_mfma<<<(N + 63) / 64, 256, 0, stream>>>(xb, aggb, Wb1l, Wb1r, b1, hb, N);

    // layer 2: project first (linearity of mean-agg), then gather on 64 dims
    gemm2_mfma<<<(N + 63) / 64, 256, 0, stream>>>(hb, Wb2, tb, ubuf, N);
    agg2_kernel<<<(N * 32 + 255) / 256, 256, 0, stream>>>((const unsigned*)tb, ubuf, b2,
                                                          rowptr, eidx, out, N);
}

// Round 4
// 246.689 us; speedup vs baseline: 15.0639x; 1.3470x over previous
//
#include <hip/hip_runtime.h>
#include <hip/hip_bf16.h>

#define N_NODES 50000

typedef __attribute__((ext_vector_type(8))) __bf16 bf16x8;
typedef __attribute__((ext_vector_type(4))) float f32x4;

__device__ __forceinline__ unsigned short f2bf(float f) {
    union { float f; unsigned u; } c{f};
    unsigned u = c.u;
    return (unsigned short)((u + 0x7FFFu + ((u >> 16) & 1u)) >> 16);
}
__device__ __forceinline__ float bf2f(unsigned short h) {
    union { unsigned u; float f; } c{(unsigned)h << 16};
    return c.f;
}

// ---------------- CSR build ----------------
__global__ void hist_kernel(const int* __restrict__ dst, int* __restrict__ cnt, int E) {
    int e = blockIdx.x * blockDim.x + threadIdx.x;
    if (e < E) atomicAdd(&cnt[dst[e]], 1);
}

// phase 1: per-block (256-elt) sums
__global__ __launch_bounds__(256) void scan_part_kernel(const int* __restrict__ cnt,
                                                        int* __restrict__ part, int N) {
    const int tid = threadIdx.x;
    int i = blockIdx.x * 256 + tid;
    int v = (i < N) ? cnt[i] : 0;
    // wave reduce
#pragma unroll
    for (int o = 1; o < 64; o <<= 1) v += __shfl_down(v, o, 64);
    __shared__ int ws[4];
    if ((tid & 63) == 0) ws[tid >> 6] = v;
    __syncthreads();
    if (tid == 0) part[blockIdx.x] = ws[0] + ws[1] + ws[2] + ws[3];
}

// phase 2: scan the partials (<=256) in one block -> exclusive offsets
__global__ __launch_bounds__(256) void scan_off_kernel(int* __restrict__ part, int P) {
    const int tid = threadIdx.x;
    int v = (tid < P) ? part[tid] : 0;
    __shared__ int s[256];
    s[tid] = v;
    __syncthreads();
    for (int o = 1; o < 256; o <<= 1) {
        int t = (tid >= o) ? s[tid - o] : 0;
        __syncthreads();
        s[tid] += t;
        __syncthreads();
    }
    if (tid < P) part[tid] = s[tid] - v;  // exclusive
}

// phase 3: block-local scan + offset -> rowptr
__global__ __launch_bounds__(256) void scan_final_kernel(const int* __restrict__ cnt,
        const int* __restrict__ part, int* __restrict__ rowptr, int N) {
    const int tid = threadIdx.x;
    int i = blockIdx.x * 256 + tid;
    int v = (i < N) ? cnt[i] : 0;
    __shared__ int s[256];
    s[tid] = v;
    __syncthreads();
    for (int o = 1; o < 256; o <<= 1) {
        int t = (tid >= o) ? s[tid - o] : 0;
        __syncthreads();
        s[tid] += t;
        __syncthreads();
    }
    int off = part[blockIdx.x];
    if (i < N) rowptr[i] = off + s[tid] - v;
    if (i == N - 1) rowptr[N] = off + s[tid];
}

__global__ void fill_kernel(const int* __restrict__ src, const int* __restrict__ dst,
                            const int* __restrict__ rowptr, int* __restrict__ cursor,
                            int* __restrict__ eidx, int E) {
    int e = blockIdx.x * blockDim.x + threadIdx.x;
    if (e < E) {
        int d = dst[e];
        int pos = rowptr[d] + atomicAdd(&cursor[d], 1);
        eidx[pos] = src[e];
    }
}

// ---------------- convert x (f32 -> packed bf16) ----------------
__global__ void cvt_x_kernel(const float* __restrict__ x, unsigned* __restrict__ xb,
                             int total) {
    int t = blockIdx.x * blockDim.x + threadIdx.x;
    if (t < total) {
        float2 v = reinterpret_cast<const float2*>(x)[t];
        xb[t] = (unsigned)f2bf(v.x) | ((unsigned)f2bf(v.y) << 16);
    }
}

// ---------------- weight prep: fragment-order bf16 ----------------
// Layout: Wb[((cb*(K/8) + kb)*16 + colin)*8 + j] = W[kb*8 + j][cb*16 + colin]
__global__ void prep_w_kernel(const float* __restrict__ W1l, const float* __restrict__ W1r,
                              const float* __restrict__ W2l, const float* __restrict__ W2r,
                              unsigned short* __restrict__ Wb1l,
                              unsigned short* __restrict__ Wb1r,
                              unsigned short* __restrict__ Wb2) {
    int t = blockIdx.x * blockDim.x + threadIdx.x;
    if (t >= 12288) return;
    int g = t & 4095;
    int colin = g & 15;
    int rest = g >> 4;
    if (t < 4096) {            // W1l: K=128 (KB8=16), N=256
        int kb = rest & 15, cb = rest >> 4;
        int col = cb * 16 + colin;
#pragma unroll
        for (int j = 0; j < 8; ++j) Wb1l[g * 8 + j] = f2bf(W1l[(kb * 8 + j) * 256 + col]);
    } else if (t < 8192) {     // W1r
        int kb = rest & 15, cb = rest >> 4;
        int col = cb * 16 + colin;
#pragma unroll
        for (int j = 0; j < 8; ++j) Wb1r[g * 8 + j] = f2bf(W1r[(kb * 8 + j) * 256 + col]);
    } else {                   // [W2l | W2r]: K=256 (KB8=32), 8 col-blocks
        int kb = rest & 31, cb = rest >> 5;
        const float* W = (cb < 4) ? W2l : W2r;
        int col = (cb < 4) ? (cb * 16 + colin) : ((cb - 4) * 16 + colin);
#pragma unroll
        for (int j = 0; j < 8; ++j) Wb2[g * 8 + j] = f2bf(W[(kb * 8 + j) * 64 + col]);
    }
}

// ---------------- gather-mean of xb (d=128 bf16), one wave/node -------------
__global__ __launch_bounds__(256) void agg1_kernel(const unsigned* __restrict__ xb,
        const int* __restrict__ rowptr, const int* __restrict__ eidx,
        unsigned* __restrict__ aggb, int N) {
    int t = blockIdx.x * 256 + threadIdx.x;
    int n = t >> 6, lane = t & 63;
    if (n >= N) return;
    int b = rowptr[n], e = rowptr[n + 1];
    float a0 = 0.0f, a1 = 0.0f;
    int j = b;
    for (; j + 1 < e; j += 2) {
        unsigned v0 = xb[(size_t)eidx[j] * 64 + lane];
        unsigned v1 = xb[(size_t)eidx[j + 1] * 64 + lane];
        a0 += bf2f(v0 & 0xFFFF) + bf2f(v1 & 0xFFFF);
        a1 += bf2f(v0 >> 16) + bf2f(v1 >> 16);
    }
    if (j < e) {
        unsigned v = xb[(size_t)eidx[j] * 64 + lane];
        a0 += bf2f(v & 0xFFFF);
        a1 += bf2f(v >> 16);
    }
    float rd = 1.0f / (float)max(e - b, 1);
    aggb[(size_t)n * 64 + lane] = (unsigned)f2bf(a0 * rd) | ((unsigned)f2bf(a1 * rd) << 16);
}

// ---------------- layer 1 MFMA: hb = relu(aggb@W1l + xb@W1r + b1) -----------
// block = 4 waves; wave = 16 rows x 256 cols. No LDS, no barriers.
__global__ __launch_bounds__(256) void gemm1_mfma(
        const unsigned short* __restrict__ xb, const unsigned short* __restrict__ aggb,
        const unsigned short* __restrict__ Wb1l, const unsigned short* __restrict__ Wb1r,
        const float* __restrict__ b1, unsigned short* __restrict__ hb, int M) {
    const int tid = threadIdx.x;
    const int wave = tid >> 6, lane = tid & 63;
    const int l16 = lane & 15, lq = lane >> 4;
    const int base_row = blockIdx.x * 64 + wave * 16;
    const int row_a = min(base_row + l16, M - 1);

    f32x4 acc[16];
#pragma unroll
    for (int i = 0; i < 16; ++i) acc[i] = (f32x4){0.f, 0.f, 0.f, 0.f};

#pragma unroll
    for (int s = 0; s < 2; ++s) {
        const unsigned short* A = (s == 0) ? aggb : xb;
        const bf16x8* W = reinterpret_cast<const bf16x8*>((s == 0) ? Wb1l : Wb1r);
#pragma unroll
        for (int ks = 0; ks < 4; ++ks) {
            bf16x8 a = *reinterpret_cast<const bf16x8*>(A + (size_t)row_a * 128 + ks * 32 + lq * 8);
            int wb = (ks * 4 + lq) * 16 + l16;
#pragma unroll
            for (int cb = 0; cb < 16; ++cb) {
                bf16x8 bfr = W[cb * 256 + wb];
                acc[cb] = __builtin_amdgcn_mfma_f32_16x16x32_bf16(a, bfr, acc[cb], 0, 0, 0);
            }
        }
    }

#pragma unroll
    for (int cb = 0; cb < 16; ++cb) {
        int col = cb * 16 + l16;
        float bias = b1[col];
#pragma unroll
        for (int r = 0; r < 4; ++r) {
            int row = base_row + lq * 4 + r;
            if (row < M) {
                float v = acc[cb][r] + bias;
                hb[(size_t)row * 256 + col] = f2bf(v > 0.0f ? v : 0.0f);
            }
        }
    }
}

// ---------------- layer 2 MFMA: [t|u] = hb @ [W2l|W2r] ----------------------
// t (cols 0..63) -> bf16 tb; u (cols 64..127) -> f32 u.
__global__ __launch_bounds__(256) void gemm2_mfma(
        const unsigned short* __restrict__ hb, const unsigned short* __restrict__ Wb2,
        unsigned short* __restrict__ tb, float* __restrict__ u, int M) {
    const int tid = threadIdx.x;
    const int wave = tid >> 6, lane = tid & 63;
    const int l16 = lane & 15, lq = lane >> 4;
    const int base_row = blockIdx.x * 64 + wave * 16;
    const int row_a = min(base_row + l16, M - 1);

    f32x4 acc[8];
#pragma unroll
    for (int i = 0; i < 8; ++i) acc[i] = (f32x4){0.f, 0.f, 0.f, 0.f};

    const bf16x8* W = reinterpret_cast<const bf16x8*>(Wb2);
#pragma unroll
    for (int ks = 0; ks < 8; ++ks) {
        bf16x8 a = *reinterpret_cast<const bf16x8*>(hb + (size_t)row_a * 256 + ks * 32 + lq * 8);
        int wb = (ks * 4 + lq) * 16 + l16;
#pragma unroll
        for (int cb = 0; cb < 8; ++cb) {
            bf16x8 bfr = W[cb * 512 + wb];
            acc[cb] = __builtin_amdgcn_mfma_f32_16x16x32_bf16(a, bfr, acc[cb], 0, 0, 0);
        }
    }

#pragma unroll
    for (int cb = 0; cb < 8; ++cb) {
#pragma unroll
        for (int r = 0; r < 4; ++r) {
            int row = base_row + lq * 4 + r;
            if (row >= M) continue;
            float v = acc[cb][r];
            if (cb < 4) tb[(size_t)row * 64 + cb * 16 + l16] = f2bf(v);
            else        u[(size_t)row * 64 + (cb - 4) * 16 + l16] = v;
        }
    }
}

// ---------------- gather-mean of tb (d=64) + u + b2 -> out ------------------
// 32 lanes per node (2 cols each).
__global__ __launch_bounds__(256) void agg2_kernel(const unsigned* __restrict__ tb,
        const float* __restrict__ u, const float* __restrict__ b2,
        const int* __restrict__ rowptr, const int* __restrict__ eidx,
        float* __restrict__ out, int N) {
    int t = blockIdx.x * 256 + threadIdx.x;
    int n = t >> 5, l = t & 31;
    if (n >= N) return;
    int b = rowptr[n], e = rowptr[n + 1];
    float a0 = 0.0f, a1 = 0.0f;
    int j = b;
    for (; j + 1 < e; j += 2) {
        unsigned v0 = tb[(size_t)eidx[j] * 32 + l];
        unsigned v1 = tb[(size_t)eidx[j + 1] * 32 + l];
        a0 += bf2f(v0 & 0xFFFF) + bf2f(v1 & 0xFFFF);
        a1 += bf2f(v0 >> 16) + bf2f(v1 >> 16);
    }
    if (j < e) {
        unsigned v = tb[(size_t)eidx[j] * 32 + l];
        a0 += bf2f(v & 0xFFFF);
        a1 += bf2f(v >> 16);
    }
    float rd = 1.0f / (float)max(e - b, 1);
    float2 uu = reinterpret_cast<const float2*>(u)[(size_t)n * 32 + l];
    float2 bb = reinterpret_cast<const float2*>(b2)[l];
    float2 o = {a0 * rd + uu.x + bb.x, a1 * rd + uu.y + bb.y};
    reinterpret_cast<float2*>(out)[(size_t)n * 32 + l] = o;
}

extern "C" void kernel_launch(void* const* d_in, const int* in_sizes, int n_in,
                              void* d_out, int out_size, void* d_ws, size_t ws_size,
                              hipStream_t stream) {
    const float* x   = (const float*)d_in[0];
    const int*   ei  = (const int*)d_in[1];
    const float* W1l = (const float*)d_in[2];
    const float* W1r = (const float*)d_in[3];
    const float* b1  = (const float*)d_in[4];
    const float* W2l = (const float*)d_in[5];
    const float* W2r = (const float*)d_in[6];
    const float* b2  = (const float*)d_in[7];
    float* out = (float*)d_out;

    const int E = in_sizes[1] / 2;
    const int N = N_NODES;
    const int* src = ei;
    const int* dst = ei + E;
    const int SCAN_BLOCKS = (N + 255) / 256;  // 196

    // workspace layout (bytes)
    char* ws = (char*)d_ws;
    int* cnt    = (int*)(ws);
    int* cursor = (int*)(ws + 200000);
    int* rowptr = (int*)(ws + 400000);
    int* part   = (int*)(ws + 600064);
    int* eidx   = (int*)(ws + 601088);
    size_t off = 601088 + 4 * (size_t)E;
    off = (off + 15) & ~(size_t)15;
    unsigned short* xb   = (unsigned short*)(ws + off);  off += (size_t)N * 128 * 2;
    unsigned short* aggb = (unsigned short*)(ws + off);  off += (size_t)N * 128 * 2;
    unsigned short* hb   = (unsigned short*)(ws + off);  off += (size_t)N * 256 * 2;
    unsigned short* tb   = (unsigned short*)(ws + off);  off += (size_t)N * 64 * 2;
    float*          ubuf = (float*)(ws + off);           off += (size_t)N * 64 * 4;
    unsigned short* Wb1l = (unsigned short*)(ws + off);  off += 128 * 256 * 2;
    unsigned short* Wb1r = (unsigned short*)(ws + off);  off += 128 * 256 * 2;
    unsigned short* Wb2  = (unsigned short*)(ws + off);  off += 256 * 128 * 2;

    hipMemsetAsync(d_ws, 0, 400000, stream);  // cnt + cursor

    hist_kernel<<<(E + 255) / 256, 256, 0, stream>>>(dst, cnt, E);
    scan_part_kernel<<<SCAN_BLOCKS, 256, 0, stream>>>(cnt, part, N);
    scan_off_kernel<<<1, 256, 0, stream>>>(part, SCAN_BLOCKS);
    scan_final_kernel<<<SCAN_BLOCKS, 256, 0, stream>>>(cnt, part, rowptr, N);
    fill_kernel<<<(E + 255) / 256, 256, 0, stream>>>(src, dst, rowptr, cursor, eidx, E);

    cvt_x_kernel<<<(N * 64 + 255) / 256, 256, 0, stream>>>(x, (unsigned*)xb, N * 64);
    prep_w_kernel<<<48, 256, 0, stream>>>(W1l, W1r, W2l, W2r, Wb1l, Wb1r, Wb2);

    // layer 1
    agg1_kernel<<<(N * 64 + 255) / 256, 256, 0, stream>>>((const unsigned*)xb, rowptr, eidx,
                                                          (unsigned*)aggb, N);
    gemm1_mfma<<<(N + 63) / 64, 256, 0, stream>>>(xb, aggb, Wb1l, Wb1r, b1, hb, N);

    // layer 2: project first (linearity of mean-agg), then gather on 64 dims
    gemm2_mfma<<<(N + 63) / 64, 256, 0, stream>>>(hb, Wb2, tb, ubuf, N);
    agg2_kernel<<<(N * 32 + 255) / 256, 256, 0, stream>>>((const unsigned*)tb, ubuf, b2,
                                                          rowptr, eidx, out, N);
}